// Round 1
// baseline (928.938 us; speedup 1.0000x reference)
//
#include <hip/hip_runtime.h>
#include <math.h>

#define N_PTS 8192
#define ICP_STEPS 21      // STEPLIM + 1 scan iterations
#define ICP_TOL 1e-4

struct IcpState { double err; int done; int pad; };

// ---------------------------------------------------------------------------
// init: pc = p1 (as float4), nn = all-ones sentinel, state reset
// ---------------------------------------------------------------------------
__global__ __launch_bounds__(256) void icp_init(const float* __restrict__ p1,
                                                float4* __restrict__ pc,
                                                unsigned long long* __restrict__ nn,
                                                IcpState* __restrict__ st) {
  int t = blockIdx.x * 256 + threadIdx.x;   // grid covers exactly N_PTS
  pc[t] = make_float4(p1[3*t], p1[3*t+1], p1[3*t+2], 0.f);
  nn[t] = ~0ull;
  if (t == 0) { st->err = 0.0; st->done = 0; }
}

// ---------------------------------------------------------------------------
// NN search: 32 query-groups x 32 candidate-slices = 1024 blocks.
// Each thread owns one query, scans 256 LDS-staged candidates (wave-uniform
// broadcast reads). Cross-slice argmin via atomicMin on packed
// (ordered-float(d2'), idx) u64 -> lowest index wins ties like jnp.argmin.
// d2' = |b|^2 - 2 a.b  (|a|^2 dropped: constant per query, argmin-invariant)
// ---------------------------------------------------------------------------
__global__ __launch_bounds__(256) void icp_nn(const float* __restrict__ p2,
                                              const float4* __restrict__ pc,
                                              unsigned long long* __restrict__ nn,
                                              const IcpState* __restrict__ st) {
  if (st->done) return;                      // uniform across grid
  __shared__ float4 cand[256];
  const int tid = threadIdx.x;
  const int qg  = blockIdx.x & 31;
  const int cs  = blockIdx.x >> 5;
  const int c0  = cs << 8;
  {
    int c = c0 + tid;
    float x = p2[3*c], y = p2[3*c+1], z = p2[3*c+2];
    cand[tid] = make_float4(x, y, z, x*x + y*y + z*z);
  }
  __syncthreads();
  const int q = (qg << 8) + tid;
  float4 a = pc[q];
  float ax = -2.f*a.x, ay = -2.f*a.y, az = -2.f*a.z;
  float best = __builtin_inff();
  int bidx = 0;
  #pragma unroll 8
  for (int i = 0; i < 256; ++i) {
    float4 c = cand[i];
    float d = fmaf(ax, c.x, fmaf(ay, c.y, fmaf(az, c.z, c.w)));
    if (d < best) { best = d; bidx = c0 + i; }
  }
  unsigned u = __float_as_uint(best);
  u ^= (unsigned)((int)u >> 31) | 0x80000000u;   // monotone float->uint map
  atomicMin(nn + q, ((unsigned long long)u << 32) | (unsigned)bidx);
}

// ---------------------------------------------------------------------------
// 3x3 Kabsch from raw sums (all double). s[0]=sum dmin, s[1..3]=sum src,
// s[4..6]=sum dst, s[7..15]=sum src_i*dst_j (row-major).
// R = V diag(1,1,detV) U~^T with U~ right-handed; equals reference's
// V diag(1,1,sign(det U det V)) U^T.
// ---------------------------------------------------------------------------
__device__ void kabsch_solve(const double* s, double* R, double* T) {
  const double n = (double)N_PTS;
  double c1[3] = { s[1]/n, s[2]/n, s[3]/n };
  double c2[3] = { s[4]/n, s[5]/n, s[6]/n };
  double H[3][3];
  #pragma unroll
  for (int i = 0; i < 3; ++i)
    #pragma unroll
    for (int j = 0; j < 3; ++j)
      H[i][j] = s[7 + 3*i + j] - n * c1[i] * c2[j];

  // A = H^T H (symmetric PSD)
  double A[3][3];
  #pragma unroll
  for (int i = 0; i < 3; ++i)
    #pragma unroll
    for (int j = 0; j < 3; ++j)
      A[i][j] = H[0][i]*H[0][j] + H[1][i]*H[1][j] + H[2][i]*H[2][j];

  double V[3][3] = {{1,0,0},{0,1,0},{0,0,1}};
  for (int sweep = 0; sweep < 15; ++sweep) {
    double off = A[0][1]*A[0][1] + A[0][2]*A[0][2] + A[1][2]*A[1][2];
    double dg  = A[0][0]*A[0][0] + A[1][1]*A[1][1] + A[2][2]*A[2][2] + 1e-300;
    if (off <= 1e-30 * dg) break;
    #pragma unroll
    for (int pi = 0; pi < 3; ++pi) {
      const int p = (pi == 2) ? 1 : 0;
      const int q = (pi == 0) ? 1 : 2;
      double apq = A[p][q];
      if (fabs(apq) < 1e-300) continue;
      double tau = (A[q][q] - A[p][p]) / (2.0 * apq);
      double tt  = (tau >= 0.0 ? 1.0 : -1.0) / (fabs(tau) + sqrt(1.0 + tau*tau));
      double c   = 1.0 / sqrt(1.0 + tt*tt);
      double sn  = tt * c;
      double app = A[p][p], aqq = A[q][q];
      A[p][p] = app - tt*apq;
      A[q][q] = aqq + tt*apq;
      A[p][q] = A[q][p] = 0.0;
      const int r = 3 - p - q;
      double arp = A[r][p], arq = A[r][q];
      A[r][p] = A[p][r] = c*arp - sn*arq;
      A[r][q] = A[q][r] = sn*arp + c*arq;
      #pragma unroll
      for (int k = 0; k < 3; ++k) {
        double vkp = V[k][p], vkq = V[k][q];
        V[k][p] = c*vkp - sn*vkq;
        V[k][q] = sn*vkp + c*vkq;
      }
    }
  }
  // sort eigenpairs descending
  double lam[3] = { A[0][0], A[1][1], A[2][2] };
  int ord[3] = {0,1,2};
  for (int i = 0; i < 2; ++i)
    for (int j = i+1; j < 3; ++j)
      if (lam[ord[j]] > lam[ord[i]]) { int t2 = ord[i]; ord[i] = ord[j]; ord[j] = t2; }
  double v0[3] = { V[0][ord[0]], V[1][ord[0]], V[2][ord[0]] };
  double v1[3] = { V[0][ord[1]], V[1][ord[1]], V[2][ord[1]] };
  double v2[3] = { V[0][ord[2]], V[1][ord[2]], V[2][ord[2]] };
  double detV = v0[0]*(v1[1]*v2[2] - v1[2]*v2[1])
              - v0[1]*(v1[0]*v2[2] - v1[2]*v2[0])
              + v0[2]*(v1[0]*v2[1] - v1[1]*v2[0]);
  detV = (detV >= 0.0) ? 1.0 : -1.0;

  double u0[3], u1[3], u2[3];
  #pragma unroll
  for (int i = 0; i < 3; ++i) u0[i] = H[i][0]*v0[0] + H[i][1]*v0[1] + H[i][2]*v0[2];
  double n0 = sqrt(u0[0]*u0[0] + u0[1]*u0[1] + u0[2]*u0[2]);
  if (!(n0 > 1e-150)) {   // degenerate: fall back to identity
    for (int i = 0; i < 9; ++i) R[i] = (i % 4 == 0) ? 1.0 : 0.0;
    for (int i = 0; i < 3; ++i) T[i] = c2[i] - c1[i];
    return;
  }
  #pragma unroll
  for (int i = 0; i < 3; ++i) u0[i] /= n0;
  #pragma unroll
  for (int i = 0; i < 3; ++i) u1[i] = H[i][0]*v1[0] + H[i][1]*v1[1] + H[i][2]*v1[2];
  double d10 = u1[0]*u0[0] + u1[1]*u0[1] + u1[2]*u0[2];
  #pragma unroll
  for (int i = 0; i < 3; ++i) u1[i] -= d10 * u0[i];
  double n1 = sqrt(u1[0]*u1[0] + u1[1]*u1[1] + u1[2]*u1[2]);
  if (!(n1 > 1e-150)) {
    for (int i = 0; i < 9; ++i) R[i] = (i % 4 == 0) ? 1.0 : 0.0;
    for (int i = 0; i < 3; ++i) T[i] = c2[i] - c1[i];
    return;
  }
  #pragma unroll
  for (int i = 0; i < 3; ++i) u1[i] /= n1;
  u2[0] = u0[1]*u1[2] - u0[2]*u1[1];
  u2[1] = u0[2]*u1[0] - u0[0]*u1[2];
  u2[2] = u0[0]*u1[1] - u0[1]*u1[0];

  #pragma unroll
  for (int i = 0; i < 3; ++i)
    #pragma unroll
    for (int j = 0; j < 3; ++j)
      R[3*i + j] = v0[i]*u0[j] + v1[i]*u1[j] + detV * v2[i]*u2[j];
  #pragma unroll
  for (int i = 0; i < 3; ++i)
    T[i] = c2[i] - (R[3*i]*c1[0] + R[3*i+1]*c1[1] + R[3*i+2]*c1[2]);
}

// 16-value double block reduction (256 threads = 4 waves)
__device__ void block_reduce16(double* v, double* tot, double* lds) {
  const int lane = threadIdx.x & 63;
  const int w    = threadIdx.x >> 6;
  #pragma unroll
  for (int q = 0; q < 16; ++q) {
    double x = v[q];
    for (int o = 32; o > 0; o >>= 1) x += __shfl_down(x, o, 64);
    if (lane == 0) lds[w*16 + q] = x;
  }
  __syncthreads();
  if (threadIdx.x < 16)
    tot[threadIdx.x] = lds[threadIdx.x] + lds[16 + threadIdx.x]
                     + lds[32 + threadIdx.x] + lds[48 + threadIdx.x];
  __syncthreads();
}

// ---------------------------------------------------------------------------
// finish: gather matched points, reduce sums, Kabsch, update pc, done-logic,
// and clear nn for the next iteration.
// ---------------------------------------------------------------------------
__global__ __launch_bounds__(256) void icp_finish(const float* __restrict__ p2,
                                                  float4* __restrict__ pc,
                                                  unsigned long long* __restrict__ nn,
                                                  IcpState* __restrict__ st) {
  __shared__ double lds[64];
  __shared__ double tot[16];
  __shared__ double RT[12];
  if (st->done) return;                     // uniform

  double v[16];
  #pragma unroll
  for (int q = 0; q < 16; ++q) v[q] = 0.0;

  for (int n = threadIdx.x; n < N_PTS; n += 256) {
    unsigned idx = (unsigned)(nn[n] & 0xffffffffull);
    float4 a4 = pc[n];
    double ax = a4.x, ay = a4.y, az = a4.z;
    double bx = p2[3*idx], by = p2[3*idx+1], bz = p2[3*idx+2];
    double d2 = (ax*ax + ay*ay + az*az) + (bx*bx + by*by + bz*bz)
              - 2.0*(ax*bx + ay*by + az*bz);
    v[0]  += sqrt(fmax(d2, 1e-12));
    v[1]  += ax;    v[2]  += ay;    v[3]  += az;
    v[4]  += bx;    v[5]  += by;    v[6]  += bz;
    v[7]  += ax*bx; v[8]  += ax*by; v[9]  += ax*bz;
    v[10] += ay*bx; v[11] += ay*by; v[12] += ay*bz;
    v[13] += az*bx; v[14] += az*by; v[15] += az*bz;
  }
  block_reduce16(v, tot, lds);

  if (threadIdx.x == 0) {
    double R[9], T[3];
    kabsch_solve(tot, R, T);
    double errnew = tot[0];                 // B == 1
    double errold = st->err;
    st->err  = errnew;
    st->done = (fabs(errold - errnew) < ICP_TOL) ? 1 : 0;
    #pragma unroll
    for (int i = 0; i < 9; ++i) RT[i] = R[i];
    RT[9] = T[0]; RT[10] = T[1]; RT[11] = T[2];
  }
  __syncthreads();

  // done_old was false here, so the update always applies (reference: pc_new)
  for (int n = threadIdx.x; n < N_PTS; n += 256) {
    float4 a4 = pc[n];
    double x = a4.x, y = a4.y, z = a4.z;
    float nx = (float)(RT[0]*x + RT[1]*y + RT[2]*z + RT[9]);
    float ny = (float)(RT[3]*x + RT[4]*y + RT[5]*z + RT[10]);
    float nz = (float)(RT[6]*x + RT[7]*y + RT[8]*z + RT[11]);
    pc[n] = make_float4(nx, ny, nz, 0.f);
    nn[n] = ~0ull;                          // reset for next iteration
  }
}

// ---------------------------------------------------------------------------
// final: Kabsch(p1 -> pc), write [R | t] as 3x4 row-major (12 floats)
// ---------------------------------------------------------------------------
__global__ __launch_bounds__(256) void icp_final(const float* __restrict__ p1,
                                                 const float4* __restrict__ pc,
                                                 float* __restrict__ out) {
  __shared__ double lds[64];
  __shared__ double tot[16];
  double v[16];
  #pragma unroll
  for (int q = 0; q < 16; ++q) v[q] = 0.0;

  for (int n = threadIdx.x; n < N_PTS; n += 256) {
    double ax = p1[3*n], ay = p1[3*n+1], az = p1[3*n+2];
    float4 b4 = pc[n];
    double bx = b4.x, by = b4.y, bz = b4.z;
    v[1]  += ax;    v[2]  += ay;    v[3]  += az;
    v[4]  += bx;    v[5]  += by;    v[6]  += bz;
    v[7]  += ax*bx; v[8]  += ax*by; v[9]  += ax*bz;
    v[10] += ay*bx; v[11] += ay*by; v[12] += ay*bz;
    v[13] += az*bx; v[14] += az*by; v[15] += az*bz;
  }
  block_reduce16(v, tot, lds);

  if (threadIdx.x == 0) {
    double R[9], T[3];
    kabsch_solve(tot, R, T);
    #pragma unroll
    for (int i = 0; i < 3; ++i) {
      out[4*i + 0] = (float)R[3*i + 0];
      out[4*i + 1] = (float)R[3*i + 1];
      out[4*i + 2] = (float)R[3*i + 2];
      out[4*i + 3] = (float)T[i];
    }
  }
}

// ---------------------------------------------------------------------------
extern "C" void kernel_launch(void* const* d_in, const int* in_sizes, int n_in,
                              void* d_out, int out_size, void* d_ws, size_t ws_size,
                              hipStream_t stream) {
  const float* p1 = (const float*)d_in[0];
  const float* p2 = (const float*)d_in[1];
  float* out = (float*)d_out;

  char* ws = (char*)d_ws;
  unsigned long long* nn = (unsigned long long*)ws;          // 64 KiB
  float4* pc = (float4*)(ws + 64*1024);                      // 128 KiB
  IcpState* st = (IcpState*)(ws + 192*1024);                 // 16 B

  icp_init<<<N_PTS/256, 256, 0, stream>>>(p1, pc, nn, st);
  for (int it = 0; it < ICP_STEPS; ++it) {
    icp_nn<<<1024, 256, 0, stream>>>(p2, pc, nn, st);
    icp_finish<<<1, 256, 0, stream>>>(p2, pc, nn, st);
  }
  icp_final<<<1, 256, 0, stream>>>(p1, pc, out);
}

// Round 2
// 637.248 us; speedup vs baseline: 1.4577x; 1.4577x over previous
//
#include <hip/hip_runtime.h>
#include <math.h>

#define N_PTS 8192
#define ICP_STEPS 21      // STEPLIM + 1 scan iterations
#define ICP_TOL 1e-4

// NN geometry: 4 query-groups (2048 q each) x 64 candidate-slices (128 c each)
#define NN_QPT 8          // queries per thread
#define NN_CSL 128        // candidates per slice
#define NN_BLOCKS 256
#define RED_BLOCKS 32

struct IcpState {
  double err;
  int done; int pad;
  double Rc[9];   // cumulative rotation (row-major): pc = Rc*p1 + tc
  double tc[3];
};

// ---------------------------------------------------------------------------
// init: nn sentinel, state = identity transform, accumulators zeroed
// ---------------------------------------------------------------------------
__global__ __launch_bounds__(256) void icp_init(unsigned long long* __restrict__ nn,
                                                IcpState* __restrict__ st,
                                                double* __restrict__ acc,
                                                unsigned* __restrict__ ticket) {
  int t = blockIdx.x * 256 + threadIdx.x;
  nn[t] = ~0ull;
  if (blockIdx.x == 0 && threadIdx.x == 0) {
    st->err = 0.0; st->done = 0;
    #pragma unroll
    for (int i = 0; i < 9; ++i) st->Rc[i] = (i % 4 == 0) ? 1.0 : 0.0;
    st->tc[0] = st->tc[1] = st->tc[2] = 0.0;
    #pragma unroll
    for (int i = 0; i < 16; ++i) acc[i] = 0.0;
    *ticket = 0u;
  }
}

// ---------------------------------------------------------------------------
// NN search. Each thread owns 8 queries (positions computed on the fly from
// p1 via the cumulative transform), scans 128 LDS-staged candidates
// (wave-uniform broadcast reads -> conflict-free). Cross-slice argmin via
// atomicMin on packed (ordered-float(d2'), idx) u64 -> lowest index wins
// ties like jnp.argmin. d2' = |b|^2 - 2 a.b (|a|^2 dropped: argmin-invariant)
// ---------------------------------------------------------------------------
__global__ __launch_bounds__(256) void icp_nn(const float* __restrict__ p1,
                                              const float* __restrict__ p2,
                                              unsigned long long* __restrict__ nn,
                                              const IcpState* __restrict__ st) {
  if (st->done) return;                      // uniform across grid
  __shared__ float4 cand[NN_CSL];
  const int tid = threadIdx.x;
  const int qg  = blockIdx.x >> 6;           // 0..3
  const int cs  = blockIdx.x & 63;           // 0..63
  const int c0  = cs * NN_CSL;
  if (tid < NN_CSL) {
    int c = c0 + tid;
    float x = p2[3*c], y = p2[3*c+1], z = p2[3*c+2];
    cand[tid] = make_float4(x, y, z, x*x + y*y + z*z);
  }
  const double R0 = st->Rc[0], R1 = st->Rc[1], R2 = st->Rc[2];
  const double R3 = st->Rc[3], R4 = st->Rc[4], R5 = st->Rc[5];
  const double R6 = st->Rc[6], R7 = st->Rc[7], R8 = st->Rc[8];
  const double T0 = st->tc[0], T1 = st->tc[1], T2 = st->tc[2];

  float ax[NN_QPT], ay[NN_QPT], az[NN_QPT], best[NN_QPT];
  int bidx[NN_QPT];
  const int qbase = (qg << 11) + tid;        // qg*2048 + tid
  #pragma unroll
  for (int j = 0; j < NN_QPT; ++j) {
    int q = qbase + (j << 8);
    double X = p1[3*q], Y = p1[3*q+1], Z = p1[3*q+2];
    float qx = (float)(R0*X + R1*Y + R2*Z + T0);
    float qy = (float)(R3*X + R4*Y + R5*Z + T1);
    float qz = (float)(R6*X + R7*Y + R8*Z + T2);
    ax[j] = -2.f*qx; ay[j] = -2.f*qy; az[j] = -2.f*qz;
    best[j] = __builtin_inff(); bidx[j] = 0;
  }
  __syncthreads();

  #pragma unroll 4
  for (int i = 0; i < NN_CSL; ++i) {
    float4 c = cand[i];
    #pragma unroll
    for (int j = 0; j < NN_QPT; ++j) {
      float d = fmaf(ax[j], c.x, fmaf(ay[j], c.y, fmaf(az[j], c.z, c.w)));
      if (d < best[j]) { best[j] = d; bidx[j] = c0 + i; }
    }
  }
  #pragma unroll
  for (int j = 0; j < NN_QPT; ++j) {
    unsigned u = __float_as_uint(best[j]);
    u ^= (unsigned)((int)u >> 31) | 0x80000000u;   // monotone float->uint map
    atomicMin(nn + qbase + (j << 8),
              ((unsigned long long)u << 32) | (unsigned)bidx[j]);
  }
}

// ---------------------------------------------------------------------------
// 3x3 Kabsch from raw sums (all double). s[0]=sum dmin, s[1..3]=sum src,
// s[4..6]=sum dst, s[7..15]=sum src_i*dst_j (row-major).
// ---------------------------------------------------------------------------
__device__ void kabsch_solve(const double* s, double* R, double* T) {
  const double n = (double)N_PTS;
  double c1[3] = { s[1]/n, s[2]/n, s[3]/n };
  double c2[3] = { s[4]/n, s[5]/n, s[6]/n };
  double H[3][3];
  #pragma unroll
  for (int i = 0; i < 3; ++i)
    #pragma unroll
    for (int j = 0; j < 3; ++j)
      H[i][j] = s[7 + 3*i + j] - n * c1[i] * c2[j];

  double A[3][3];
  #pragma unroll
  for (int i = 0; i < 3; ++i)
    #pragma unroll
    for (int j = 0; j < 3; ++j)
      A[i][j] = H[0][i]*H[0][j] + H[1][i]*H[1][j] + H[2][i]*H[2][j];

  double V[3][3] = {{1,0,0},{0,1,0},{0,0,1}};
  for (int sweep = 0; sweep < 12; ++sweep) {
    double off = A[0][1]*A[0][1] + A[0][2]*A[0][2] + A[1][2]*A[1][2];
    double dg  = A[0][0]*A[0][0] + A[1][1]*A[1][1] + A[2][2]*A[2][2] + 1e-300;
    if (off <= 1e-30 * dg) break;
    #pragma unroll
    for (int pi = 0; pi < 3; ++pi) {
      const int p = (pi == 2) ? 1 : 0;
      const int q = (pi == 0) ? 1 : 2;
      double apq = A[p][q];
      if (fabs(apq) < 1e-300) continue;
      double tau = (A[q][q] - A[p][p]) / (2.0 * apq);
      double tt  = (tau >= 0.0 ? 1.0 : -1.0) / (fabs(tau) + sqrt(1.0 + tau*tau));
      double c   = 1.0 / sqrt(1.0 + tt*tt);
      double sn  = tt * c;
      A[p][p] -= tt*apq;
      A[q][q] += tt*apq;
      A[p][q] = A[q][p] = 0.0;
      const int r = 3 - p - q;
      double arp = A[r][p], arq = A[r][q];
      A[r][p] = A[p][r] = c*arp - sn*arq;
      A[r][q] = A[q][r] = sn*arp + c*arq;
      #pragma unroll
      for (int k = 0; k < 3; ++k) {
        double vkp = V[k][p], vkq = V[k][q];
        V[k][p] = c*vkp - sn*vkq;
        V[k][q] = sn*vkp + c*vkq;
      }
    }
  }
  double lam[3] = { A[0][0], A[1][1], A[2][2] };
  int ord[3] = {0,1,2};
  for (int i = 0; i < 2; ++i)
    for (int j = i+1; j < 3; ++j)
      if (lam[ord[j]] > lam[ord[i]]) { int t2 = ord[i]; ord[i] = ord[j]; ord[j] = t2; }
  double v0[3] = { V[0][ord[0]], V[1][ord[0]], V[2][ord[0]] };
  double v1[3] = { V[0][ord[1]], V[1][ord[1]], V[2][ord[1]] };
  double v2[3] = { V[0][ord[2]], V[1][ord[2]], V[2][ord[2]] };
  double detV = v0[0]*(v1[1]*v2[2] - v1[2]*v2[1])
              - v0[1]*(v1[0]*v2[2] - v1[2]*v2[0])
              + v0[2]*(v1[0]*v2[1] - v1[1]*v2[0]);
  detV = (detV >= 0.0) ? 1.0 : -1.0;

  double u0[3], u1[3], u2[3];
  #pragma unroll
  for (int i = 0; i < 3; ++i) u0[i] = H[i][0]*v0[0] + H[i][1]*v0[1] + H[i][2]*v0[2];
  double n0 = sqrt(u0[0]*u0[0] + u0[1]*u0[1] + u0[2]*u0[2]);
  if (!(n0 > 1e-150)) {
    for (int i = 0; i < 9; ++i) R[i] = (i % 4 == 0) ? 1.0 : 0.0;
    for (int i = 0; i < 3; ++i) T[i] = c2[i] - c1[i];
    return;
  }
  #pragma unroll
  for (int i = 0; i < 3; ++i) u0[i] /= n0;
  #pragma unroll
  for (int i = 0; i < 3; ++i) u1[i] = H[i][0]*v1[0] + H[i][1]*v1[1] + H[i][2]*v1[2];
  double d10 = u1[0]*u0[0] + u1[1]*u0[1] + u1[2]*u0[2];
  #pragma unroll
  for (int i = 0; i < 3; ++i) u1[i] -= d10 * u0[i];
  double n1 = sqrt(u1[0]*u1[0] + u1[1]*u1[1] + u1[2]*u1[2]);
  if (!(n1 > 1e-150)) {
    for (int i = 0; i < 9; ++i) R[i] = (i % 4 == 0) ? 1.0 : 0.0;
    for (int i = 0; i < 3; ++i) T[i] = c2[i] - c1[i];
    return;
  }
  #pragma unroll
  for (int i = 0; i < 3; ++i) u1[i] /= n1;
  u2[0] = u0[1]*u1[2] - u0[2]*u1[1];
  u2[1] = u0[2]*u1[0] - u0[0]*u1[2];
  u2[2] = u0[0]*u1[1] - u0[1]*u1[0];

  #pragma unroll
  for (int i = 0; i < 3; ++i)
    #pragma unroll
    for (int j = 0; j < 3; ++j)
      R[3*i + j] = v0[i]*u0[j] + v1[i]*u1[j] + detV * v2[i]*u2[j];
  #pragma unroll
  for (int i = 0; i < 3; ++i)
    T[i] = c2[i] - (R[3*i]*c1[0] + R[3*i+1]*c1[1] + R[3*i+2]*c1[2]);
}

// 16-value double block reduction (256 threads = 4 waves); result in tot[16]
__device__ void block_reduce16(double* v, double* tot, double* lds) {
  const int lane = threadIdx.x & 63;
  const int w    = threadIdx.x >> 6;
  #pragma unroll
  for (int q = 0; q < 16; ++q) {
    double x = v[q];
    for (int o = 32; o > 0; o >>= 1) x += __shfl_down(x, o, 64);
    if (lane == 0) lds[w*16 + q] = x;
  }
  __syncthreads();
  if (threadIdx.x < 16)
    tot[threadIdx.x] = lds[threadIdx.x] + lds[16 + threadIdx.x]
                     + lds[32 + threadIdx.x] + lds[48 + threadIdx.x];
  __syncthreads();
}

// ---------------------------------------------------------------------------
// reduce + solve (fused via last-block ticket): 32 blocks, 1 point/thread.
// Gathers matched pairs, reduces the 16 Kabsch sums via atomicAdd(double),
// last block solves 3x3 Kabsch, composes the cumulative transform, updates
// err/done, and resets acc/ticket for the next iteration. Also resets nn.
// ---------------------------------------------------------------------------
__global__ __launch_bounds__(256) void icp_reduce_solve(
    const float* __restrict__ p1, const float* __restrict__ p2,
    unsigned long long* __restrict__ nn, IcpState* __restrict__ st,
    double* __restrict__ acc, unsigned* __restrict__ ticket) {
  if (st->done) return;                     // uniform
  __shared__ double lds[64];
  __shared__ double tot[16];
  __shared__ int lastFlag;
  const int tid = threadIdx.x;
  const int n   = blockIdx.x * 256 + tid;

  const double R0 = st->Rc[0], R1 = st->Rc[1], R2 = st->Rc[2];
  const double R3 = st->Rc[3], R4 = st->Rc[4], R5 = st->Rc[5];
  const double R6 = st->Rc[6], R7 = st->Rc[7], R8 = st->Rc[8];
  const double T0 = st->tc[0], T1 = st->tc[1], T2 = st->tc[2];

  double X = p1[3*n], Y = p1[3*n+1], Z = p1[3*n+2];
  // fp32-rounded source position (matches what NN used and reference's pc)
  float sxf = (float)(R0*X + R1*Y + R2*Z + T0);
  float syf = (float)(R3*X + R4*Y + R5*Z + T1);
  float szf = (float)(R6*X + R7*Y + R8*Z + T2);
  unsigned idx = (unsigned)(nn[n] & 0xffffffffull);
  nn[n] = ~0ull;                            // reset for next iteration

  double ax = sxf, ay = syf, az = szf;
  double bx = p2[3*idx], by = p2[3*idx+1], bz = p2[3*idx+2];
  double d2 = (ax*ax + ay*ay + az*az) + (bx*bx + by*by + bz*bz)
            - 2.0*(ax*bx + ay*by + az*bz);
  double v[16];
  v[0]  = sqrt(fmax(d2, 1e-12));
  v[1]  = ax;    v[2]  = ay;    v[3]  = az;
  v[4]  = bx;    v[5]  = by;    v[6]  = bz;
  v[7]  = ax*bx; v[8]  = ax*by; v[9]  = ax*bz;
  v[10] = ay*bx; v[11] = ay*by; v[12] = ay*bz;
  v[13] = az*bx; v[14] = az*by; v[15] = az*bz;
  block_reduce16(v, tot, lds);

  if (tid < 16) atomicAdd(acc + tid, tot[tid]);
  __threadfence();
  __syncthreads();
  if (tid == 0) {
    unsigned old = atomicAdd(ticket, 1u);
    lastFlag = (old == RED_BLOCKS - 1) ? 1 : 0;
  }
  __syncthreads();
  if (!lastFlag) return;

  // ---- last block: read totals coherently, solve, compose, reset ----
  if (tid < 16) tot[tid] = atomicAdd(acc + tid, 0.0);   // device-scope read
  __syncthreads();
  if (tid == 0) {
    double s[16];
    #pragma unroll
    for (int i = 0; i < 16; ++i) s[i] = tot[i];
    double R[9], T[3];
    kabsch_solve(s, R, T);
    // compose: pc_new = R*(Rc*p1 + tc) + T = (R*Rc)*p1 + (R*tc + T)
    double Rc[9] = {R0,R1,R2,R3,R4,R5,R6,R7,R8};
    double tc[3] = {T0,T1,T2};
    #pragma unroll
    for (int i = 0; i < 3; ++i) {
      #pragma unroll
      for (int j = 0; j < 3; ++j)
        st->Rc[3*i+j] = R[3*i+0]*Rc[0+j] + R[3*i+1]*Rc[3+j] + R[3*i+2]*Rc[6+j];
      st->tc[i] = R[3*i+0]*tc[0] + R[3*i+1]*tc[1] + R[3*i+2]*tc[2] + T[i];
    }
    double errnew = s[0];                   // B == 1
    st->done = (fabs(st->err - errnew) < ICP_TOL) ? 1 : 0;
    st->err  = errnew;
    // reset accumulators for next iteration
    #pragma unroll
    for (int i = 0; i < 16; ++i) acc[i] = 0.0;
    *ticket = 0u;
  }
}

// ---------------------------------------------------------------------------
// final: kabsch(p1, Rc*p1+tc) == (Rc, tc) exactly -> just emit [R | t] 3x4
// ---------------------------------------------------------------------------
__global__ __launch_bounds__(64) void icp_final(const IcpState* __restrict__ st,
                                                float* __restrict__ out) {
  if (threadIdx.x == 0) {
    #pragma unroll
    for (int i = 0; i < 3; ++i) {
      out[4*i + 0] = (float)st->Rc[3*i + 0];
      out[4*i + 1] = (float)st->Rc[3*i + 1];
      out[4*i + 2] = (float)st->Rc[3*i + 2];
      out[4*i + 3] = (float)st->tc[i];
    }
  }
}

// ---------------------------------------------------------------------------
extern "C" void kernel_launch(void* const* d_in, const int* in_sizes, int n_in,
                              void* d_out, int out_size, void* d_ws, size_t ws_size,
                              hipStream_t stream) {
  const float* p1 = (const float*)d_in[0];
  const float* p2 = (const float*)d_in[1];
  float* out = (float*)d_out;

  char* ws = (char*)d_ws;
  unsigned long long* nn = (unsigned long long*)ws;            // 64 KiB
  IcpState* st = (IcpState*)(ws + 64*1024);                    // 128 B
  double* acc = (double*)(ws + 64*1024 + 256);                 // 128 B
  unsigned* ticket = (unsigned*)(ws + 64*1024 + 512);          // 4 B

  icp_init<<<N_PTS/256, 256, 0, stream>>>(nn, st, acc, ticket);
  for (int it = 0; it < ICP_STEPS; ++it) {
    icp_nn<<<NN_BLOCKS, 256, 0, stream>>>(p1, p2, nn, st);
    icp_reduce_solve<<<RED_BLOCKS, 256, 0, stream>>>(p1, p2, nn, st, acc, ticket);
  }
  icp_final<<<1, 64, 0, stream>>>(st, out);
}